// Round 7
// baseline (339.085 us; speedup 1.0000x reference)
//
#include <hip/hip_runtime.h>
#include <math.h>

// ---------------- problem constants ----------------
#define TSTEPS 40
#define GATED  30
#define BATCH  4096
#define XD     150
#define HD     150
#define HP     160      // padded hidden/x dim
#define PITCHW 328      // Wc row pitch (bf16 elems, 656 B)
#define SXP    328      // sxh row pitch (bf16 elems)
#define WLP    166      // wldsh row pitch (bf16 elems) - odd-ish word stride for banks
#define WROWS  704      // 640 gate rows + 64 w1 rows
#define ROWS   16       // batch rows per block (MFMA M)
#define NT     512      // 8 waves
#define NBLK   (BATCH / ROWS)  // 256 blocks -> 1 per CU

#define S1P    68       // st1 pitch (fp32, 272 B = 16B-aligned)
#define S2P    28       // st2 pitch (fp32, 112 B = 16B-aligned)
#define W2P    52       // sw2p pitch (fp32, 208 B = 16B-aligned)

#define LOG2E 1.44269504088896f

// output packing (flat fp32)
#define OFF_OUTPUTS 614400
#define OFF_YS      25190400

typedef float  floatx4 __attribute__((ext_vector_type(4)));
typedef short  shortx8 __attribute__((ext_vector_type(8)));

__device__ __forceinline__ unsigned short bf16_rne(float f) {
    union { float f; unsigned int u; } v; v.f = f;
    unsigned int u = v.u;
    return (unsigned short)((u + 0x7fffu + ((u >> 16) & 1u)) >> 16);
}
__device__ __forceinline__ unsigned int pk2bf(float a, float b) {
    return (unsigned int)bf16_rne(a) | ((unsigned int)bf16_rne(b) << 16);
}
__device__ __forceinline__ float rcp_f(float x) {
    return __builtin_amdgcn_rcpf(x);
}
// sigmoid(x+bias) with prescaled bias pb = -LOG2E*bias
__device__ __forceinline__ float sig2(float acc, float pb) {
    return rcp_f(1.0f + exp2f(fmaf(acc, -LOG2E, pb)));
}
// tanh(x+bias) with prescaled bias pb = 2*LOG2E*bias
__device__ __forceinline__ float tanh2pre(float acc, float pb) {
    float a = fmaf(acc, 2.0f * LOG2E, pb);
    a = fminf(fmaxf(a, -44.0f), 44.0f);
    float t = exp2f(a);
    return (t - 1.0f) * rcp_f(t + 1.0f);
}
__device__ __forceinline__ float tanh2(float x) {
    float a = fminf(fmaxf(2.0f * LOG2E * x, -44.0f), 44.0f);
    float t = exp2f(a);
    return (t - 1.0f) * rcp_f(t + 1.0f);
}
// raw barrier: LDS-ordering only, leaves global loads/stores in flight
__device__ __forceinline__ void bar_lds() {
    asm volatile("s_waitcnt lgkmcnt(0)\n\ts_barrier" ::: "memory");
}

// ---------------- weight packing (unchanged) ----------------
__global__ void pack_weights(const float* __restrict__ w_ih, const float* __restrict__ w_hh,
                             const float* __restrict__ b_ih, const float* __restrict__ b_hh,
                             const float* __restrict__ w1,
                             unsigned short* __restrict__ Wc, float* __restrict__ bcp) {
    int idx = blockIdx.x * blockDim.x + threadIdx.x;
    int stride = gridDim.x * blockDim.x;
    for (int i = idx; i < WROWS * PITCHW; i += stride) {
        int j = i / PITCHW, k = i - j * PITCHW;
        float v = 0.0f;
        if (j < 640) {
            int tp = j / HP, u = j - tp * HP;
            if (u < 150) {
                int src = tp * 150 + u;
                if (k < 150)                    v = w_ih[src * 150 + k];
                else if (k >= 160 && k < 310)   v = w_hh[src * 150 + (k - 160)];
            }
        } else {
            int j1 = j - 640;
            if (j1 < 50) {
                if (k < 150)                    v = w1[j1 * 300 + 150 + k];   // x part
                else if (k >= 160 && k < 310)   v = w1[j1 * 300 + (k - 160)]; // h part
            }
        }
        Wc[i] = bf16_rne(v);
    }
    for (int i = idx; i < 640; i += stride) {
        int tp = i / HP, u = i - tp * HP;
        bcp[i] = (u < 150) ? (b_ih[tp * 150 + u] + b_hh[tp * 150 + u]) : 0.0f;
    }
}

// ---------------- main persistent LSTM kernel ----------------
// R6: extra tile's x-part (kb0-4) in registers (efx[5]); wldsh holds only the
// h-part (kb5-9) -> wlds LDS reads halved (10 -> 5 b128/wave/step).
// exp2-native activations with prescaled biases; outh moved to stop_gate.
__global__ __launch_bounds__(NT, 2)
void lstm_main(const float* __restrict__ x,
               const unsigned short* __restrict__ Wc,
               const float* __restrict__ bcp,
               float* __restrict__ outputs) {
    __shared__ unsigned short sxh[2][ROWS][SXP];   // bf16 [x(0..149)|0|h(160..309)|0]
    __shared__ float sge[ROWS][4][33];             // extra-chunk pre-acts (type, col 0..31)
    __shared__ unsigned short wldsh[8][16][WLP];   // extra tiles, h-part only (42.5 KB)
    __shared__ float bcs[640];

    const int tid  = threadIdx.x;
    const int lane = tid & 63;
    const int wv   = tid >> 6;     // wave 0..7
    const int lrow = lane & 15;    // tile row
    const int lq   = lane >> 4;    // quad 0..3
    const int row0 = blockIdx.x * ROWS;
    const int ty   = wv >> 1;      // extra-tile type 0..3
    const int ch   = wv & 1;       // extra-tile col half
    const int ET   = 10 * ty + 8 + ch;   // this wave's extra tile

    // ---- one-time init ----
    for (int i = tid; i < 2 * ROWS * SXP; i += NT) {
        int b = i / (ROWS * SXP);
        int rem = i - b * (ROWS * SXP);
        int r = rem / SXP, k = rem - r * SXP;
        if (k >= 150) sxh[b][r][k] = 0;   // h0=0, pads=0
    }
    // stage x_0 into buffer 0
    for (int i = tid; i < ROWS * 75; i += NT) {
        int rr = i / 75, kk = i - rr * 75;
        float2 v = *(const float2*)(x + ((size_t)row0 + rr) * XD + 2 * kk);
        *(unsigned int*)&sxh[0][rr][2 * kk] = pk2bf(v.x, v.y);
    }
    // copy extra tiles' h-part (cols 160..319) into wldsh[w][r][0..159]
    for (int i = tid; i < 8 * 16 * 80; i += NT) {
        int w = i / (16 * 80);
        int rem = i - w * (16 * 80);
        int r = rem / 80, k = rem - r * 80;   // k counts uint pairs
        int et = 10 * (w >> 1) + 8 + (w & 1);
        *(unsigned int*)&wldsh[w][r][2 * k] =
            *(const unsigned int*)&Wc[(size_t)(et * 16 + r) * PITCHW + 160 + 2 * k];
    }
    for (int i = tid; i < 640; i += NT) bcs[i] = bcp[i];

    // ---- register weights: 4 chunk tiles full-K + extra tile x-part ----
    shortx8 bfr[40];
#pragma unroll
    for (int j = 0; j < 4; ++j) {
        const unsigned short* wp =
            Wc + (size_t)((10 * j + wv) * 16 + lrow) * PITCHW + lq * 8;
#pragma unroll
        for (int kb = 0; kb < 10; ++kb)
            bfr[j * 10 + kb] = *(const shortx8*)(wp + kb * 32);
    }
    shortx8 efx[5];
    {
        const unsigned short* wpe =
            Wc + (size_t)(ET * 16 + lrow) * PITCHW + lq * 8;
#pragma unroll
        for (int kb = 0; kb < 5; ++kb)
            efx[kb] = *(const shortx8*)(wpe + kb * 32);
    }

    __syncthreads();

    // ---- loop-invariant hoists (prescaled biases) ----
    const int uq = wv * 16 + lrow;                 // this lane's chunk u (<128)
    const float bcq0s = -LOG2E * bcs[uq];
    const float bcq1s = -LOG2E * bcs[160 + uq];
    const float bcq2s = 2.0f * LOG2E * bcs[320 + uq];
    const float bcq3s = -LOG2E * bcs[480 + uq];
    const int ce_c = tid & 31;                     // extra col 0..31
    const int ue = 128 + ce_c;                     // extra u (128..159)
    const int re = tid >> 5;                       // extra row 0..15
    const float bce0s = -LOG2E * bcs[ue];
    const float bce1s = -LOG2E * bcs[160 + ue];
    const float bce2s = 2.0f * LOG2E * bcs[320 + ue];
    const float bce3s = -LOG2E * bcs[480 + ue];
    const bool  ewr   = (ue < 150);
    // x-prefetch per-thread constants
    const int pr0 = tid / 75,          pk0 = tid % 75;
    const int pr1 = (tid + 512) / 75,  pk1 = (tid + 512) % 75;
    const int pr2 = (tid + 1024) / 75, pk2 = (tid + 1024) % 75;  // valid if tid<176

    // incremental output pointers
    float* outc = outputs + (size_t)(row0 + lq * 4) * HD + uq;   // rows lq*4+rg
    float* oute = outputs + (size_t)(row0 + re) * HD + ue;       // extra (t-1 lag)

    float cr[4] = {0.f, 0.f, 0.f, 0.f};
    float cex = 0.f;

    unsigned short (*sxc)[SXP] = sxh[0];
    unsigned short (*sxn)[SXP] = sxh[1];

    // =================== recurrent loop ===================
    for (int t = 0; t < TSTEPS; ++t) {
        // ---- prefetch x_{t+1} into registers (stays in flight) ----
        float2 px0, px1, px2;
        const bool pf = (t + 1 < TSTEPS);
        if (pf) {
            const float* xn = x + ((size_t)(t + 1) * BATCH + row0) * XD;
            px0 = *(const float2*)(xn + pr0 * XD + 2 * pk0);
            px1 = *(const float2*)(xn + pr1 * XD + 2 * pk1);
            if (tid < 176) px2 = *(const float2*)(xn + pr2 * XD + 2 * pk2);
        }

        // ---- issue sge reads early (extra pre-acts of step t-1) ----
        float ge0, ge1, ge2, ge3;
        if (t > 0) {
            ge0 = sge[re][0][ce_c];
            ge1 = sge[re][1][ce_c];
            ge2 = sge[re][2][ce_c];
            ge3 = sge[re][3][ce_c];
        }

        // ---- MFMA kb 0..8 (reads sxc cols 0..287 only) ----
        floatx4 acc[5];
#pragma unroll
        for (int j = 0; j < 5; ++j) acc[j] = (floatx4){0.f, 0.f, 0.f, 0.f};
#pragma unroll
        for (int kb = 0; kb < 9; ++kb) {
            shortx8 a = *(const shortx8*)&sxc[lrow][kb * 32 + lq * 8];
#pragma unroll
            for (int j = 0; j < 4; ++j)
                acc[j] = __builtin_amdgcn_mfma_f32_16x16x32_bf16(
                    a, bfr[j * 10 + kb], acc[j], 0, 0, 0);
            shortx8 b4 = (kb < 5) ? efx[kb]
                : *(const shortx8*)&wldsh[wv][lrow][(kb - 5) * 32 + lq * 8];
            acc[4] = __builtin_amdgcn_mfma_f32_16x16x32_bf16(a, b4, acc[4], 0, 0, 0);
        }

        // ---- extra pointwise for step t-1 (overlaps MFMAs above) ----
        if (t > 0) {
            float si = sig2(ge0, bce0s);
            float sf = sig2(ge1, bce1s);
            float tg = tanh2pre(ge2, bce2s);
            float so = sig2(ge3, bce3s);
            float cn = sf * cex + si * tg;
            cex = cn;
            float h = so * tanh2(cn);
            sxc[re][HP + ue] = bf16_rne(h);
            if (ewr) oute[0] = h;
        }
        bar_lds();   // B2: extra-h visible to all waves

        // ---- MFMA kb 9 (reads sxc cols 288..319) ----
        {
            shortx8 a = *(const shortx8*)&sxc[lrow][9 * 32 + lq * 8];
#pragma unroll
            for (int j = 0; j < 4; ++j)
                acc[j] = __builtin_amdgcn_mfma_f32_16x16x32_bf16(
                    a, bfr[j * 10 + 9], acc[j], 0, 0, 0);
            shortx8 b4 = *(const shortx8*)&wldsh[wv][lrow][4 * 32 + lq * 8];
            acc[4] = __builtin_amdgcn_mfma_f32_16x16x32_bf16(a, b4, acc[4], 0, 0, 0);
        }

        // ---- extra-tile pre-acts -> sge (read next iteration) ----
#pragma unroll
        for (int rg = 0; rg < 4; ++rg)
            sge[lq * 4 + rg][ty][ch * 16 + lrow] = acc[4][rg];

        // ---- chunk pointwise -> sxn h[0:128] + outputs ----
#pragma unroll
        for (int rg = 0; rg < 4; ++rg) {
            float si = sig2(acc[0][rg], bcq0s);
            float sf = sig2(acc[1][rg], bcq1s);
            float tg = tanh2pre(acc[2][rg], bcq2s);
            float so = sig2(acc[3][rg], bcq3s);
            float cn = sf * cr[rg] + si * tg;
            cr[rg] = cn;
            float h = so * tanh2(cn);
            sxn[lq * 4 + rg][HP + uq] = bf16_rne(h);
            outc[rg * HD] = h;                       // uq<128<150 always valid
        }
        // ---- stage x_{t+1} into sxn ----
        if (pf) {
            *(unsigned int*)&sxn[pr0][2 * pk0] = pk2bf(px0.x, px0.y);
            *(unsigned int*)&sxn[pr1][2 * pk1] = pk2bf(px1.x, px1.y);
            if (tid < 176)
                *(unsigned int*)&sxn[pr2][2 * pk2] = pk2bf(px2.x, px2.y);
        }
        bar_lds();   // B1: sxn (x_{t+1}, h[0:128]) + sge complete

        // swap buffers, advance output pointers
        { unsigned short (*tmp)[SXP] = sxc; sxc = sxn; sxn = tmp; }
        outc += (size_t)BATCH * HD;
        if (t > 0) oute += (size_t)BATCH * HD;
    }

    // ---- epilogue: extra pointwise for t = TSTEPS-1 ----
    {
        float si = sig2(sge[re][0][ce_c], bce0s);
        float sf = sig2(sge[re][1][ce_c], bce1s);
        float tg = tanh2pre(sge[re][2][ce_c], bce2s);
        float so = sig2(sge[re][3][ce_c], bce3s);
        float cn = sf * cex + si * tg;
        float h = so * tanh2(cn);
        if (ewr) oute[0] = h;
    }
}

// ---------------- stop-gate MLP v3 ----------------
// 480 blocks x 4 jobs; bias+relu fused into MFMA epilogue (no layer1 phase);
// layer2 computes j-pairs per thread (st1 row regs reused); outh written here.
#define SG_JOBS 4
__global__ __launch_bounds__(256, 2)
void stop_gate(const float* __restrict__ x,
               const unsigned short* __restrict__ Wc,
               const float* __restrict__ b1,
               const float* __restrict__ w2, const float* __restrict__ b2,
               const float* __restrict__ w3, const float* __restrict__ b3,
               const float* __restrict__ outputs, float* __restrict__ outh,
               float* __restrict__ ys) {
    __shared__ unsigned short sA[64][SXP];   // [x|h] bf16, 42 KB
    __shared__ float st1[64][S1P];           // 17.4 KB (cols 50..63 computed zeros)
    __shared__ float st2[64][S2P];           // 7.2 KB (cols 25..27 zero)
    __shared__ float sw2p[26][W2P];          // row 25 = 0; cols 50,51 = 0
    __shared__ float sw3p[2][S2P];           // cols 25..27 = 0
    __shared__ float b1s[64], sb2[26], sb3[2];

    const int tid  = threadIdx.x;
    const int lane = tid & 63;
    const int wv   = tid >> 6;     // wave 0..3
    const int lrow = lane & 15;
    const int lq   = lane >> 4;

    // ---- one-time init ----
    // zero only sA pad cols: 150..159 and 310..319 (uint pairs)
    for (int i = tid; i < 64 * 10; i += 256) {
        int r = i / 10, c = i - r * 10;
        int col = (c < 5) ? (150 + 2 * c) : (310 + 2 * (c - 5));
        *(unsigned int*)&sA[r][col] = 0;
    }
    // zero st2 pad cols 26..27 (col 25 is written as computed zero)
    for (int i = tid; i < 64 * 3; i += 256)
        st2[i / 3][25 + i % 3] = 0.0f;
    // weights (sw2p row 25 = zeros; sb2[25] = 0)
    for (int i = tid; i < 26 * W2P; i += 256) {
        int j = i / W2P, k = i - j * W2P;
        sw2p[j][k] = (j < 25 && k < 50) ? w2[j * 50 + k] : 0.0f;
    }
    if (tid < 2 * S2P) {
        int j = tid / S2P, k = tid - j * S2P;
        sw3p[j][k] = (k < 25) ? w3[j * 25 + k] : 0.0f;
    }
    if (tid < 64) b1s[tid] = (tid < 50) ? b1[tid] : 0.0f;
    if (tid < 26) sb2[tid] = (tid < 25) ? b2[tid] : 0.0f;
    if (tid < 2)  sb3[tid] = b3[tid];
    __syncthreads();

    for (int jb = 0; jb < SG_JOBS; ++jb) {
        const int job  = blockIdx.x * SG_JOBS + jb;   // 0..1919
        const int t    = job >> 6;                    // 0..29
        const int row0 = (job & 63) * 64;             // batch row base

        // ---- stage [x_t | h_t] bf16; write outh for t == GATED-1 ----
        for (int i = tid; i < 64 * 75; i += 256) {
            int row = i / 75, kk = i - row * 75;
            size_t base = ((size_t)t * BATCH + row0 + row) * (size_t)XD;
            float2 xv = *(const float2*)(x + base + 2 * kk);
            float2 hv = *(const float2*)(outputs + base + 2 * kk);   // HD==XD
            *(unsigned int*)&sA[row][2 * kk]      = pk2bf(xv.x, xv.y);
            *(unsigned int*)&sA[row][HP + 2 * kk] = pk2bf(hv.x, hv.y);
            if (t == GATED - 1)
                *(float2*)&outh[(size_t)(row0 + row) * HD + 2 * kk] = hv;
        }
        __syncthreads();

        // ---- w1 MFMAs (wave wv: rows 16wv..16wv+15, ct=0..3), fused bias+relu ----
#pragma unroll
        for (int ct = 0; ct < 4; ++ct) {
            const unsigned short* wp1 =
                Wc + (size_t)(640 + ct * 16 + lrow) * PITCHW + lq * 8;
            floatx4 aw = {0.f, 0.f, 0.f, 0.f};
#pragma unroll
            for (int kb = 0; kb < 10; ++kb) {
                shortx8 a = *(const shortx8*)&sA[wv * 16 + lrow][kb * 32 + lq * 8];
                shortx8 b = *(const shortx8*)(wp1 + kb * 32);
                aw = __builtin_amdgcn_mfma_f32_16x16x32_bf16(a, b, aw, 0, 0, 0);
            }
            float bv = b1s[ct * 16 + lrow];
#pragma unroll
            for (int rg = 0; rg < 4; ++rg) {
                float v = aw[rg] + bv;
                st1[wv * 16 + lq * 4 + rg][ct * 16 + lrow] = v > 0.0f ? v : 0.0f;
            }
        }
        __syncthreads();

        // ---- layer2: j-pairs per thread, st1 row reused, + relu ----
        for (int u = tid; u < 64 * 13; u += 256) {
            int s = u / 13, jp = u - s * 13;
            int j0 = 2 * jp, j1 = j0 + 1;       // j1 == 25 -> zero row, harmless
            float a0 = sb2[j0], a1 = sb2[j1];
#pragma unroll
            for (int m = 0; m < 13; ++m) {
                floatx4 a4  = *(const floatx4*)&st1[s][4 * m];
                floatx4 w40 = *(const floatx4*)&sw2p[j0][4 * m];
                floatx4 w41 = *(const floatx4*)&sw2p[j1][4 * m];
                a0 = fmaf(w40[0], a4[0], a0);  a1 = fmaf(w41[0], a4[0], a1);
                a0 = fmaf(w40[1], a4[1], a0);  a1 = fmaf(w41[1], a4[1], a1);
                a0 = fmaf(w40[2], a4[2], a0);  a1 = fmaf(w41[2], a4[2], a1);
                a0 = fmaf(w40[3], a4[3], a0);  a1 = fmaf(w41[3], a4[3], a1);
            }
            st2[s][j0] = a0 > 0.0f ? a0 : 0.0f;
            st2[s][j1] = a1 > 0.0f ? a1 : 0.0f;   // j1==25 writes 0
        }
        __syncthreads();

        // ---- layer3 + relu + softmax(2) ----
        if (tid < 64) {
            float z0 = sb3[0], z1 = sb3[1];
#pragma unroll
            for (int m = 0; m < 7; ++m) {
                floatx4 a4 = *(const floatx4*)&st2[tid][4 * m];
                floatx4 w0 = *(const floatx4*)&sw3p[0][4 * m];
                floatx4 w1v = *(const floatx4*)&sw3p[1][4 * m];
                z0 = fmaf(w0[0], a4[0], z0);  z1 = fmaf(w1v[0], a4[0], z1);
                z0 = fmaf(w0[1], a4[1], z0);  z1 = fmaf(w1v[1], a4[1], z1);
                z0 = fmaf(w0[2], a4[2], z0);  z1 = fmaf(w1v[2], a4[2], z1);
                z0 = fmaf(w0[3], a4[3], z0);  z1 = fmaf(w1v[3], a4[3], z1);
            }
            z0 = z0 > 0.0f ? z0 : 0.0f;
            z1 = z1 > 0.0f ? z1 : 0.0f;
            float mx = fmaxf(z0, z1);
            float e0 = __expf(z0 - mx), e1 = __expf(z1 - mx);
            float inv = rcp_f(e0 + e1);
            float2 y = {e0 * inv, e1 * inv};
            *(float2*)&ys[((size_t)t * BATCH + row0 + tid) * 2] = y;
        }
        __syncthreads();   // st2/st1/sA safe to overwrite next job
    }
}

extern "C" void kernel_launch(void* const* d_in, const int* in_sizes, int n_in,
                              void* d_out, int out_size, void* d_ws, size_t ws_size,
                              hipStream_t stream) {
    const float* x    = (const float*)d_in[0];
    const float* w_ih = (const float*)d_in[1];
    const float* w_hh = (const float*)d_in[2];
    const float* b_ih = (const float*)d_in[3];
    const float* b_hh = (const float*)d_in[4];
    const float* w1   = (const float*)d_in[5];
    const float* b1   = (const float*)d_in[6];
    const float* w2   = (const float*)d_in[7];
    const float* b2   = (const float*)d_in[8];
    const float* w3   = (const float*)d_in[9];
    const float* b3   = (const float*)d_in[10];

    float* out = (float*)d_out;
    unsigned short* Wc  = (unsigned short*)d_ws;           // 704*328 bf16
    float*          bcp = (float*)(Wc + WROWS * PITCHW);   // 640

    pack_weights<<<256, 256, 0, stream>>>(w_ih, w_hh, b_ih, b_hh, w1, Wc, bcp);

    lstm_main<<<NBLK, NT, 0, stream>>>(
        x, Wc, bcp, out + OFF_OUTPUTS);

    stop_gate<<<(GATED * 64) / SG_JOBS, 256, 0, stream>>>(
        x, Wc, b1, w2, b2, w3, b3, out + OFF_OUTPUTS, out, out + OFF_YS);
}

// Round 8
// 298.595 us; speedup vs baseline: 1.1356x; 1.1356x over previous
//
#include <hip/hip_runtime.h>
#include <math.h>

// ---------------- problem constants ----------------
#define TSTEPS 40
#define GATED  30
#define BATCH  4096
#define XD     150
#define HD     150
#define HP     160      // padded hidden/x dim
#define PITCHW 328      // Wc row pitch (bf16 elems, 656 B)
#define SXP    328      // sxh row pitch (bf16 elems)
#define WROWS  704      // 640 gate rows + 64 w1 rows
#define ROWS   16       // batch rows per block (MFMA M)
#define NT     512      // 8 waves
#define NBLK   (BATCH / ROWS)  // 256 blocks -> 1 per CU

#define S1P    68       // st1 pitch (fp32, 272 B = 16B-aligned)
#define S2P    28       // st2 pitch (fp32, 112 B = 16B-aligned)
#define W2P    52       // sw2p pitch (fp32, 208 B = 16B-aligned)

// output packing (flat fp32)
#define OFF_OUTPUTS 614400
#define OFF_YS      25190400

typedef float  floatx4 __attribute__((ext_vector_type(4)));
typedef short  shortx8 __attribute__((ext_vector_type(8)));

__device__ __forceinline__ unsigned short bf16_rne(float f) {
    union { float f; unsigned int u; } v; v.f = f;
    unsigned int u = v.u;
    return (unsigned short)((u + 0x7fffu + ((u >> 16) & 1u)) >> 16);
}
__device__ __forceinline__ unsigned int pk2bf(float a, float b) {
    return (unsigned int)bf16_rne(a) | ((unsigned int)bf16_rne(b) << 16);
}
__device__ __forceinline__ float rcp_f(float x) {
    return __builtin_amdgcn_rcpf(x);
}
__device__ __forceinline__ float sigf(float x) {
    return rcp_f(1.0f + __expf(-x));
}
__device__ __forceinline__ float tanh_fast(float x) {
    x = fminf(fmaxf(x, -15.0f), 15.0f);
    float t = __expf(2.0f * x);
    return (t - 1.0f) * rcp_f(t + 1.0f);
}
// raw barrier: LDS-ordering only, leaves global loads/stores in flight
__device__ __forceinline__ void bar_lds() {
    asm volatile("s_waitcnt lgkmcnt(0)\n\ts_barrier" ::: "memory");
}

// ---------------- weight packing (unchanged) ----------------
__global__ void pack_weights(const float* __restrict__ w_ih, const float* __restrict__ w_hh,
                             const float* __restrict__ b_ih, const float* __restrict__ b_hh,
                             const float* __restrict__ w1,
                             unsigned short* __restrict__ Wc, float* __restrict__ bcp) {
    int idx = blockIdx.x * blockDim.x + threadIdx.x;
    int stride = gridDim.x * blockDim.x;
    for (int i = idx; i < WROWS * PITCHW; i += stride) {
        int j = i / PITCHW, k = i - j * PITCHW;
        float v = 0.0f;
        if (j < 640) {
            int tp = j / HP, u = j - tp * HP;
            if (u < 150) {
                int src = tp * 150 + u;
                if (k < 150)                    v = w_ih[src * 150 + k];
                else if (k >= 160 && k < 310)   v = w_hh[src * 150 + (k - 160)];
            }
        } else {
            int j1 = j - 640;
            if (j1 < 50) {
                if (k < 150)                    v = w1[j1 * 300 + 150 + k];   // x part
                else if (k >= 160 && k < 310)   v = w1[j1 * 300 + (k - 160)]; // h part
            }
        }
        Wc[i] = bf16_rne(v);
    }
    for (int i = idx; i < 640; i += stride) {
        int tp = i / HP, u = i - tp * HP;
        bcp[i] = (u < 150) ? (b_ih[tp * 150 + u] + b_hh[tp * 150 + u]) : 0.0f;
    }
}

// ---------------- main persistent LSTM kernel ----------------
// R5-proven structure: 4 chunk tiles in registers (bfr[40] -- the exact
// register capacity; R6 proved +20 more spills), extra tile full-K from wlds.
// Cross-step pipelined extra-chunk pointwise. outh is written by stop_gate.
__global__ __launch_bounds__(NT, 2)
void lstm_main(const float* __restrict__ x,
               const unsigned short* __restrict__ Wc,
               const float* __restrict__ bcp,
               float* __restrict__ outputs) {
    __shared__ unsigned short sxh[2][ROWS][SXP];   // bf16 [x(0..149)|0|h(160..309)|0]
    __shared__ float sge[ROWS][4][33];             // extra-chunk pre-acts (type, col 0..31)
    __shared__ unsigned short wlds[8][16][SXP];    // per-wave extra tile (84 KB)
    __shared__ float bcs[640];

    const int tid  = threadIdx.x;
    const int lane = tid & 63;
    const int wv   = tid >> 6;     // wave 0..7
    const int lrow = lane & 15;    // tile row
    const int lq   = lane >> 4;    // quad 0..3
    const int row0 = blockIdx.x * ROWS;
    const int ty   = wv >> 1;      // extra-tile type 0..3
    const int ch   = wv & 1;       // extra-tile col half

    // ---- one-time init ----
    for (int i = tid; i < 2 * ROWS * SXP; i += NT) {
        int b = i / (ROWS * SXP);
        int rem = i - b * (ROWS * SXP);
        int r = rem / SXP, k = rem - r * SXP;
        if (k >= 150) sxh[b][r][k] = 0;   // h0=0, pads=0
    }
    // stage x_0 into buffer 0
    for (int i = tid; i < ROWS * 75; i += NT) {
        int rr = i / 75, kk = i - rr * 75;
        float2 v = *(const float2*)(x + ((size_t)row0 + rr) * XD + 2 * kk);
        *(unsigned int*)&sxh[0][rr][2 * kk] = pk2bf(v.x, v.y);
    }
    // copy extra tiles (==8,9 mod 10) into wlds[w]
    for (int i = tid; i < 8 * 16 * 160; i += NT) {
        int w = i / (16 * 160);
        int rem = i - w * (16 * 160);
        int r = rem / 160, k = rem - r * 160;   // k counts uint pairs
        int et = 10 * (w >> 1) + 8 + (w & 1);
        *(unsigned int*)&wlds[w][r][2 * k] =
            *(const unsigned int*)&Wc[(size_t)(et * 16 + r) * PITCHW + 2 * k];
    }
    for (int i = tid; i < 640; i += NT) bcs[i] = bcp[i];

    // ---- load this wave's 4 chunk tiles (type j, u-chunk wv) into registers ----
    shortx8 bfr[40];
#pragma unroll
    for (int j = 0; j < 4; ++j) {
        const unsigned short* wp =
            Wc + (size_t)((10 * j + wv) * 16 + lrow) * PITCHW + lq * 8;
#pragma unroll
        for (int kb = 0; kb < 10; ++kb)
            bfr[j * 10 + kb] = *(const shortx8*)(wp + kb * 32);
    }

    __syncthreads();

    // ---- loop-invariant hoists ----
    const int uq = wv * 16 + lrow;                 // this lane's chunk u (<128)
    const float bcq0 = bcs[uq];
    const float bcq1 = bcs[160 + uq];
    const float bcq2 = bcs[320 + uq];
    const float bcq3 = bcs[480 + uq];
    const int ce_c = tid & 31;                     // extra col 0..31
    const int ue = 128 + ce_c;                     // extra u (128..159)
    const int re = tid >> 5;                       // extra row 0..15
    const float bce0 = bcs[ue];
    const float bce1 = bcs[160 + ue];
    const float bce2 = bcs[320 + ue];
    const float bce3 = bcs[480 + ue];
    // x-prefetch per-thread constants
    const int pr0 = tid / 75,          pk0 = tid % 75;
    const int pr1 = (tid + 512) / 75,  pk1 = (tid + 512) % 75;
    const int pr2 = (tid + 1024) / 75, pk2 = (tid + 1024) % 75;  // valid if tid<176

    // incremental output pointer for chunk part
    float* outc = outputs + (size_t)(row0 + lq * 4) * HD + uq;   // rows lq*4+rg

    float cr[4] = {0.f, 0.f, 0.f, 0.f};
    float cex = 0.f;

    unsigned short (*sxc)[SXP] = sxh[0];
    unsigned short (*sxn)[SXP] = sxh[1];

    // =================== recurrent loop ===================
    for (int t = 0; t < TSTEPS; ++t) {
        // ---- prefetch x_{t+1} into registers (stays in flight) ----
        float2 px0, px1, px2;
        const bool pf = (t + 1 < TSTEPS);
        if (pf) {
            const float* xn = x + ((size_t)(t + 1) * BATCH + row0) * XD;
            px0 = *(const float2*)(xn + pr0 * XD + 2 * pk0);
            px1 = *(const float2*)(xn + pr1 * XD + 2 * pk1);
            if (tid < 176) px2 = *(const float2*)(xn + pr2 * XD + 2 * pk2);
        }

        // ---- issue sge reads early (extra pre-acts of step t-1) ----
        float ge0, ge1, ge2, ge3;
        if (t > 0) {
            ge0 = sge[re][0][ce_c];
            ge1 = sge[re][1][ce_c];
            ge2 = sge[re][2][ce_c];
            ge3 = sge[re][3][ce_c];
        }

        // ---- MFMA kb 0..8 (reads sxc cols 0..287 only) ----
        floatx4 acc[5];
#pragma unroll
        for (int j = 0; j < 5; ++j) acc[j] = (floatx4){0.f, 0.f, 0.f, 0.f};
#pragma unroll
        for (int kb = 0; kb < 9; ++kb) {
            shortx8 a = *(const shortx8*)&sxc[lrow][kb * 32 + lq * 8];
#pragma unroll
            for (int j = 0; j < 4; ++j)
                acc[j] = __builtin_amdgcn_mfma_f32_16x16x32_bf16(
                    a, bfr[j * 10 + kb], acc[j], 0, 0, 0);
            shortx8 b4 = *(const shortx8*)&wlds[wv][lrow][kb * 32 + lq * 8];
            acc[4] = __builtin_amdgcn_mfma_f32_16x16x32_bf16(a, b4, acc[4], 0, 0, 0);
        }

        // ---- extra pointwise for step t-1 (overlaps MFMAs above) ----
        if (t > 0) {
            float gi = ge0 + bce0;
            float gf = ge1 + bce1;
            float gg = ge2 + bce2;
            float go = ge3 + bce3;
            float cn = sigf(gf) * cex + sigf(gi) * tanh_fast(gg);
            cex = cn;
            float h = sigf(go) * tanh_fast(cn);
            sxc[re][HP + ue] = bf16_rne(h);
            if (ue < 150)
                outputs[((size_t)(t - 1) * BATCH + row0 + re) * HD + ue] = h;
        }
        bar_lds();   // B2: extra-h visible to all waves

        // ---- MFMA kb 9 (reads sxc cols 288..319) ----
        {
            shortx8 a = *(const shortx8*)&sxc[lrow][9 * 32 + lq * 8];
#pragma unroll
            for (int j = 0; j < 4; ++j)
                acc[j] = __builtin_amdgcn_mfma_f32_16x16x32_bf16(
                    a, bfr[j * 10 + 9], acc[j], 0, 0, 0);
            shortx8 b4 = *(const shortx8*)&wlds[wv][lrow][9 * 32 + lq * 8];
            acc[4] = __builtin_amdgcn_mfma_f32_16x16x32_bf16(a, b4, acc[4], 0, 0, 0);
        }

        // ---- extra-tile pre-acts -> sge (read next iteration) ----
#pragma unroll
        for (int rg = 0; rg < 4; ++rg)
            sge[lq * 4 + rg][ty][ch * 16 + lrow] = acc[4][rg];

        // ---- chunk pointwise -> sxn h[0:128] + outputs ----
#pragma unroll
        for (int rg = 0; rg < 4; ++rg) {
            float gi = acc[0][rg] + bcq0;
            float gf = acc[1][rg] + bcq1;
            float gg = acc[2][rg] + bcq2;
            float go = acc[3][rg] + bcq3;
            float cn = sigf(gf) * cr[rg] + sigf(gi) * tanh_fast(gg);
            cr[rg] = cn;
            float h = sigf(go) * tanh_fast(cn);
            sxn[lq * 4 + rg][HP + uq] = bf16_rne(h);
            outc[rg * HD] = h;                       // uq<128<150 always valid
        }
        // ---- stage x_{t+1} into sxn ----
        if (pf) {
            *(unsigned int*)&sxn[pr0][2 * pk0] = pk2bf(px0.x, px0.y);
            *(unsigned int*)&sxn[pr1][2 * pk1] = pk2bf(px1.x, px1.y);
            if (tid < 176)
                *(unsigned int*)&sxn[pr2][2 * pk2] = pk2bf(px2.x, px2.y);
        }
        bar_lds();   // B1: sxn (x_{t+1}, h[0:128]) + sge complete

        // swap buffers, advance output pointer
        { unsigned short (*tmp)[SXP] = sxc; sxc = sxn; sxn = tmp; }
        outc += (size_t)BATCH * HD;
    }

    // ---- epilogue: extra pointwise for t = TSTEPS-1 ----
    {
        float gi = sge[re][0][ce_c] + bce0;
        float gf = sge[re][1][ce_c] + bce1;
        float gg = sge[re][2][ce_c] + bce2;
        float go = sge[re][3][ce_c] + bce3;
        float cn = sigf(gf) * cex + sigf(gi) * tanh_fast(gg);
        float h = sigf(go) * tanh_fast(cn);
        if (ue < 150)
            outputs[((size_t)(TSTEPS - 1) * BATCH + row0 + re) * HD + ue] = h;
    }
}

// ---------------- stop-gate MLP v3 (unchanged from R6, verified) ----------------
// 480 blocks x 4 jobs; bias+relu fused into MFMA epilogue; layer2 j-pairs;
// outh written here (t == GATED-1 stage loop).
#define SG_JOBS 4
__global__ __launch_bounds__(256, 2)
void stop_gate(const float* __restrict__ x,
               const unsigned short* __restrict__ Wc,
               const float* __restrict__ b1,
               const float* __restrict__ w2, const float* __restrict__ b2,
               const float* __restrict__ w3, const float* __restrict__ b3,
               const float* __restrict__ outputs, float* __restrict__ outh,
               float* __restrict__ ys) {
    __shared__ unsigned short sA[64][SXP];   // [x|h] bf16, 42 KB
    __shared__ float st1[64][S1P];           // 17.4 KB (cols 50..63 computed zeros)
    __shared__ float st2[64][S2P];           // 7.2 KB (cols 25..27 zero)
    __shared__ float sw2p[26][W2P];          // row 25 = 0; cols 50,51 = 0
    __shared__ float sw3p[2][S2P];           // cols 25..27 = 0
    __shared__ float b1s[64], sb2[26], sb3[2];

    const int tid  = threadIdx.x;
    const int lane = tid & 63;
    const int wv   = tid >> 6;     // wave 0..3
    const int lrow = lane & 15;
    const int lq   = lane >> 4;

    // ---- one-time init ----
    // zero only sA pad cols: 150..159 and 310..319 (uint pairs)
    for (int i = tid; i < 64 * 10; i += 256) {
        int r = i / 10, c = i - r * 10;
        int col = (c < 5) ? (150 + 2 * c) : (310 + 2 * (c - 5));
        *(unsigned int*)&sA[r][col] = 0;
    }
    // zero st2 pad cols 25..27 (col 25 also written as computed zero)
    for (int i = tid; i < 64 * 3; i += 256)
        st2[i / 3][25 + i % 3] = 0.0f;
    // weights (sw2p row 25 = zeros; sb2[25] = 0)
    for (int i = tid; i < 26 * W2P; i += 256) {
        int j = i / W2P, k = i - j * W2P;
        sw2p[j][k] = (j < 25 && k < 50) ? w2[j * 50 + k] : 0.0f;
    }
    if (tid < 2 * S2P) {
        int j = tid / S2P, k = tid - j * S2P;
        sw3p[j][k] = (k < 25) ? w3[j * 25 + k] : 0.0f;
    }
    if (tid < 64) b1s[tid] = (tid < 50) ? b1[tid] : 0.0f;
    if (tid < 26) sb2[tid] = (tid < 25) ? b2[tid] : 0.0f;
    if (tid < 2)  sb3[tid] = b3[tid];
    __syncthreads();

    for (int jb = 0; jb < SG_JOBS; ++jb) {
        const int job  = blockIdx.x * SG_JOBS + jb;   // 0..1919
        const int t    = job >> 6;                    // 0..29
        const int row0 = (job & 63) * 64;             // batch row base

        // ---- stage [x_t | h_t] bf16; write outh for t == GATED-1 ----
        for (int i = tid; i < 64 * 75; i += 256) {
            int row = i / 75, kk = i - row * 75;
            size_t base = ((size_t)t * BATCH + row0 + row) * (size_t)XD;
            float2 xv = *(const float2*)(x + base + 2 * kk);
            float2 hv = *(const float2*)(outputs + base + 2 * kk);   // HD==XD
            *(unsigned int*)&sA[row][2 * kk]      = pk2bf(xv.x, xv.y);
            *(unsigned int*)&sA[row][HP + 2 * kk] = pk2bf(hv.x, hv.y);
            if (t == GATED - 1)
                *(float2*)&outh[(size_t)(row0 + row) * HD + 2 * kk] = hv;
        }
        __syncthreads();

        // ---- w1 MFMAs (wave wv: rows 16wv..16wv+15, ct=0..3), fused bias+relu ----
#pragma unroll
        for (int ct = 0; ct < 4; ++ct) {
            const unsigned short* wp1 =
                Wc + (size_t)(640 + ct * 16 + lrow) * PITCHW + lq * 8;
            floatx4 aw = {0.f, 0.f, 0.f, 0.f};
#pragma unroll
            for (int kb = 0; kb < 10; ++kb) {
                shortx8 a = *(const shortx8*)&sA[wv * 16 + lrow][kb * 32 + lq * 8];
                shortx8 b = *(const shortx8*)(wp1 + kb * 32);
                aw = __builtin_amdgcn_mfma_f32_16x16x32_bf16(a, b, aw, 0, 0, 0);
            }
            float bv = b1s[ct * 16 + lrow];
#pragma unroll
            for (int rg = 0; rg < 4; ++rg) {
                float v = aw[rg] + bv;
                st1[wv * 16 + lq * 4 + rg][ct * 16 + lrow] = v > 0.0f ? v : 0.0f;
            }
        }
        __syncthreads();

        // ---- layer2: j-pairs per thread, st1 row reused, + relu ----
        for (int u = tid; u < 64 * 13; u += 256) {
            int s = u / 13, jp = u - s * 13;
            int j0 = 2 * jp, j1 = j0 + 1;       // j1 == 25 -> zero row, harmless
            float a0 = sb2[j0], a1 = sb2[j1];
#pragma unroll
            for (int m = 0; m < 13; ++m) {
                floatx4 a4  = *(const floatx4*)&st1[s][4 * m];
                floatx4 w40 = *(const floatx4*)&sw2p[j0][4 * m];
                floatx4 w41 = *(const floatx4*)&sw2p[j1][4 * m];
                a0 = fmaf(w40[0], a4[0], a0);  a1 = fmaf(w41[0], a4[0], a1);
                a0 = fmaf(w40[1], a4[1], a0);  a1 = fmaf(w41[1], a4[1], a1);
                a0 = fmaf(w40[2], a4[2], a0);  a1 = fmaf(w41[2], a4[2], a1);
                a0 = fmaf(w40[3], a4[3], a0);  a1 = fmaf(w41[3], a4[3], a1);
            }
            st2[s][j0] = a0 > 0.0f ? a0 : 0.0f;
            st2[s][j1] = a1 > 0.0f ? a1 : 0.0f;   // j1==25 writes 0
        }
        __syncthreads();

        // ---- layer3 + relu + softmax(2) ----
        if (tid < 64) {
            float z0 = sb3[0], z1 = sb3[1];
#pragma unroll
            for (int m = 0; m < 7; ++m) {
                floatx4 a4 = *(const floatx4*)&st2[tid][4 * m];
                floatx4 w0 = *(const floatx4*)&sw3p[0][4 * m];
                floatx4 w1v = *(const floatx4*)&sw3p[1][4 * m];
                z0 = fmaf(w0[0], a4[0], z0);  z1 = fmaf(w1v[0], a4[0], z1);
                z0 = fmaf(w0[1], a4[1], z0);  z1 = fmaf(w1v[1], a4[1], z1);
                z0 = fmaf(w0[2], a4[2], z0);  z1 = fmaf(w1v[2], a4[2], z1);
                z0 = fmaf(w0[3], a4[3], z0);  z1 = fmaf(w1v[3], a4[3], z1);
            }
            z0 = z0 > 0.0f ? z0 : 0.0f;
            z1 = z1 > 0.0f ? z1 : 0.0f;
            float mx = fmaxf(z0, z1);
            float e0 = __expf(z0 - mx), e1 = __expf(z1 - mx);
            float inv = rcp_f(e0 + e1);
            float2 y = {e0 * inv, e1 * inv};
            *(float2*)&ys[((size_t)t * BATCH + row0 + tid) * 2] = y;
        }
        __syncthreads();   // st2/st1/sA safe to overwrite next job
    }
}

extern "C" void kernel_launch(void* const* d_in, const int* in_sizes, int n_in,
                              void* d_out, int out_size, void* d_ws, size_t ws_size,
                              hipStream_t stream) {
    const float* x    = (const float*)d_in[0];
    const float* w_ih = (const float*)d_in[1];
    const float* w_hh = (const float*)d_in[2];
    const float* b_ih = (const float*)d_in[3];
    const float* b_hh = (const float*)d_in[4];
    const float* w1   = (const float*)d_in[5];
    const float* b1   = (const float*)d_in[6];
    const float* w2   = (const float*)d_in[7];
    const float* b2   = (const float*)d_in[8];
    const float* w3   = (const float*)d_in[9];
    const float* b3   = (const float*)d_in[10];

    float* out = (float*)d_out;
    unsigned short* Wc  = (unsigned short*)d_ws;           // 704*328 bf16
    float*          bcp = (float*)(Wc + WROWS * PITCHW);   // 640

    pack_weights<<<256, 256, 0, stream>>>(w_ih, w_hh, b_ih, b_hh, w1, Wc, bcp);

    lstm_main<<<NBLK, NT, 0, stream>>>(
        x, Wc, bcp, out + OFF_OUTPUTS);

    stop_gate<<<(GATED * 64) / SG_JOBS, 256, 0, stream>>>(
        x, Wc, b1, w2, b2, w3, b3, out + OFF_OUTPUTS, out, out + OFF_YS);
}

// Round 9
// 297.846 us; speedup vs baseline: 1.1385x; 1.0025x over previous
//
#include <hip/hip_runtime.h>
#include <math.h>

// ---------------- problem constants ----------------
#define TSTEPS 40
#define GATED  30
#define BATCH  4096
#define XD     150
#define HD     150
#define HP     160      // padded hidden/x dim
#define PITCHW 328      // Wc row pitch (bf16 elems, 656 B)
#define SXP    328      // sxh row pitch (bf16 elems)
#define WROWS  704      // 640 gate rows + 64 w1 rows
#define ROWS   16       // batch rows per block (MFMA M)
#define NT     512      // 8 waves
#define NBLK   (BATCH / ROWS)  // 256 blocks -> 1 per CU

#define S1P    68       // st1 pitch (fp32, 272 B = 16B-aligned)
#define S2P    28       // st2 pitch (fp32, 112 B = 16B-aligned)
#define W2P    52       // sw2p pitch (fp32, 208 B = 16B-aligned)

// output packing (flat fp32)
#define OFF_OUTPUTS 614400
#define OFF_YS      25190400

typedef float  floatx4 __attribute__((ext_vector_type(4)));
typedef short  shortx8 __attribute__((ext_vector_type(8)));

__device__ __forceinline__ unsigned short bf16_rne(float f) {
    union { float f; unsigned int u; } v; v.f = f;
    unsigned int u = v.u;
    return (unsigned short)((u + 0x7fffu + ((u >> 16) & 1u)) >> 16);
}
__device__ __forceinline__ unsigned int pk2bf(float a, float b) {
    return (unsigned int)bf16_rne(a) | ((unsigned int)bf16_rne(b) << 16);
}
__device__ __forceinline__ float rcp_f(float x) {
    return __builtin_amdgcn_rcpf(x);
}
__device__ __forceinline__ float sigf(float x) {
    return rcp_f(1.0f + __expf(-x));
}
__device__ __forceinline__ float tanh_fast(float x) {
    x = fminf(fmaxf(x, -15.0f), 15.0f);
    float t = __expf(2.0f * x);
    return (t - 1.0f) * rcp_f(t + 1.0f);
}
// raw barrier: LDS-ordering only, leaves global loads/stores in flight
__device__ __forceinline__ void bar_lds() {
    asm volatile("s_waitcnt lgkmcnt(0)\n\ts_barrier" ::: "memory");
}

// ---------------- weight packing (unchanged) ----------------
__global__ void pack_weights(const float* __restrict__ w_ih, const float* __restrict__ w_hh,
                             const float* __restrict__ b_ih, const float* __restrict__ b_hh,
                             const float* __restrict__ w1,
                             unsigned short* __restrict__ Wc, float* __restrict__ bcp) {
    int idx = blockIdx.x * blockDim.x + threadIdx.x;
    int stride = gridDim.x * blockDim.x;
    for (int i = idx; i < WROWS * PITCHW; i += stride) {
        int j = i / PITCHW, k = i - j * PITCHW;
        float v = 0.0f;
        if (j < 640) {
            int tp = j / HP, u = j - tp * HP;
            if (u < 150) {
                int src = tp * 150 + u;
                if (k < 150)                    v = w_ih[src * 150 + k];
                else if (k >= 160 && k < 310)   v = w_hh[src * 150 + (k - 160)];
            }
        } else {
            int j1 = j - 640;
            if (j1 < 50) {
                if (k < 150)                    v = w1[j1 * 300 + 150 + k];   // x part
                else if (k >= 160 && k < 310)   v = w1[j1 * 300 + (k - 160)]; // h part
            }
        }
        Wc[i] = bf16_rne(v);
    }
    for (int i = idx; i < 640; i += stride) {
        int tp = i / HP, u = i - tp * HP;
        bcp[i] = (u < 150) ? (b_ih[tp * 150 + u] + b_hh[tp * 150 + u]) : 0.0f;
    }
}

// ---------------- main persistent LSTM kernel (byte-identical to R7) ----------------
__global__ __launch_bounds__(NT, 2)
void lstm_main(const float* __restrict__ x,
               const unsigned short* __restrict__ Wc,
               const float* __restrict__ bcp,
               float* __restrict__ outputs) {
    __shared__ unsigned short sxh[2][ROWS][SXP];   // bf16 [x(0..149)|0|h(160..309)|0]
    __shared__ float sge[ROWS][4][33];             // extra-chunk pre-acts (type, col 0..31)
    __shared__ unsigned short wlds[8][16][SXP];    // per-wave extra tile (84 KB)
    __shared__ float bcs[640];

    const int tid  = threadIdx.x;
    const int lane = tid & 63;
    const int wv   = tid >> 6;     // wave 0..7
    const int lrow = lane & 15;    // tile row
    const int lq   = lane >> 4;    // quad 0..3
    const int row0 = blockIdx.x * ROWS;
    const int ty   = wv >> 1;      // extra-tile type 0..3
    const int ch   = wv & 1;       // extra-tile col half

    // ---- one-time init ----
    for (int i = tid; i < 2 * ROWS * SXP; i += NT) {
        int b = i / (ROWS * SXP);
        int rem = i - b * (ROWS * SXP);
        int r = rem / SXP, k = rem - r * SXP;
        if (k >= 150) sxh[b][r][k] = 0;   // h0=0, pads=0
    }
    // stage x_0 into buffer 0
    for (int i = tid; i < ROWS * 75; i += NT) {
        int rr = i / 75, kk = i - rr * 75;
        float2 v = *(const float2*)(x + ((size_t)row0 + rr) * XD + 2 * kk);
        *(unsigned int*)&sxh[0][rr][2 * kk] = pk2bf(v.x, v.y);
    }
    // copy extra tiles (==8,9 mod 10) into wlds[w]
    for (int i = tid; i < 8 * 16 * 160; i += NT) {
        int w = i / (16 * 160);
        int rem = i - w * (16 * 160);
        int r = rem / 160, k = rem - r * 160;   // k counts uint pairs
        int et = 10 * (w >> 1) + 8 + (w & 1);
        *(unsigned int*)&wlds[w][r][2 * k] =
            *(const unsigned int*)&Wc[(size_t)(et * 16 + r) * PITCHW + 2 * k];
    }
    for (int i = tid; i < 640; i += NT) bcs[i] = bcp[i];

    // ---- load this wave's 4 chunk tiles (type j, u-chunk wv) into registers ----
    shortx8 bfr[40];
#pragma unroll
    for (int j = 0; j < 4; ++j) {
        const unsigned short* wp =
            Wc + (size_t)((10 * j + wv) * 16 + lrow) * PITCHW + lq * 8;
#pragma unroll
        for (int kb = 0; kb < 10; ++kb)
            bfr[j * 10 + kb] = *(const shortx8*)(wp + kb * 32);
    }

    __syncthreads();

    // ---- loop-invariant hoists ----
    const int uq = wv * 16 + lrow;                 // this lane's chunk u (<128)
    const float bcq0 = bcs[uq];
    const float bcq1 = bcs[160 + uq];
    const float bcq2 = bcs[320 + uq];
    const float bcq3 = bcs[480 + uq];
    const int ce_c = tid & 31;                     // extra col 0..31
    const int ue = 128 + ce_c;                     // extra u (128..159)
    const int re = tid >> 5;                       // extra row 0..15
    const float bce0 = bcs[ue];
    const float bce1 = bcs[160 + ue];
    const float bce2 = bcs[320 + ue];
    const float bce3 = bcs[480 + ue];
    // x-prefetch per-thread constants
    const int pr0 = tid / 75,          pk0 = tid % 75;
    const int pr1 = (tid + 512) / 75,  pk1 = (tid + 512) % 75;
    const int pr2 = (tid + 1024) / 75, pk2 = (tid + 1024) % 75;  // valid if tid<176

    // incremental output pointer for chunk part
    float* outc = outputs + (size_t)(row0 + lq * 4) * HD + uq;   // rows lq*4+rg

    float cr[4] = {0.f, 0.f, 0.f, 0.f};
    float cex = 0.f;

    unsigned short (*sxc)[SXP] = sxh[0];
    unsigned short (*sxn)[SXP] = sxh[1];

    // =================== recurrent loop ===================
    for (int t = 0; t < TSTEPS; ++t) {
        // ---- prefetch x_{t+1} into registers (stays in flight) ----
        float2 px0, px1, px2;
        const bool pf = (t + 1 < TSTEPS);
        if (pf) {
            const float* xn = x + ((size_t)(t + 1) * BATCH + row0) * XD;
            px0 = *(const float2*)(xn + pr0 * XD + 2 * pk0);
            px1 = *(const float2*)(xn + pr1 * XD + 2 * pk1);
            if (tid < 176) px2 = *(const float2*)(xn + pr2 * XD + 2 * pk2);
        }

        // ---- issue sge reads early (extra pre-acts of step t-1) ----
        float ge0, ge1, ge2, ge3;
        if (t > 0) {
            ge0 = sge[re][0][ce_c];
            ge1 = sge[re][1][ce_c];
            ge2 = sge[re][2][ce_c];
            ge3 = sge[re][3][ce_c];
        }

        // ---- MFMA kb 0..8 (reads sxc cols 0..287 only) ----
        floatx4 acc[5];
#pragma unroll
        for (int j = 0; j < 5; ++j) acc[j] = (floatx4){0.f, 0.f, 0.f, 0.f};
#pragma unroll
        for (int kb = 0; kb < 9; ++kb) {
            shortx8 a = *(const shortx8*)&sxc[lrow][kb * 32 + lq * 8];
#pragma unroll
            for (int j = 0; j < 4; ++j)
                acc[j] = __builtin_amdgcn_mfma_f32_16x16x32_bf16(
                    a, bfr[j * 10 + kb], acc[j], 0, 0, 0);
            shortx8 b4 = *(const shortx8*)&wlds[wv][lrow][kb * 32 + lq * 8];
            acc[4] = __builtin_amdgcn_mfma_f32_16x16x32_bf16(a, b4, acc[4], 0, 0, 0);
        }

        // ---- extra pointwise for step t-1 (overlaps MFMAs above) ----
        if (t > 0) {
            float gi = ge0 + bce0;
            float gf = ge1 + bce1;
            float gg = ge2 + bce2;
            float go = ge3 + bce3;
            float cn = sigf(gf) * cex + sigf(gi) * tanh_fast(gg);
            cex = cn;
            float h = sigf(go) * tanh_fast(cn);
            sxc[re][HP + ue] = bf16_rne(h);
            if (ue < 150)
                outputs[((size_t)(t - 1) * BATCH + row0 + re) * HD + ue] = h;
        }
        bar_lds();   // B2: extra-h visible to all waves

        // ---- MFMA kb 9 (reads sxc cols 288..319) ----
        {
            shortx8 a = *(const shortx8*)&sxc[lrow][9 * 32 + lq * 8];
#pragma unroll
            for (int j = 0; j < 4; ++j)
                acc[j] = __builtin_amdgcn_mfma_f32_16x16x32_bf16(
                    a, bfr[j * 10 + 9], acc[j], 0, 0, 0);
            shortx8 b4 = *(const shortx8*)&wlds[wv][lrow][9 * 32 + lq * 8];
            acc[4] = __builtin_amdgcn_mfma_f32_16x16x32_bf16(a, b4, acc[4], 0, 0, 0);
        }

        // ---- extra-tile pre-acts -> sge (read next iteration) ----
#pragma unroll
        for (int rg = 0; rg < 4; ++rg)
            sge[lq * 4 + rg][ty][ch * 16 + lrow] = acc[4][rg];

        // ---- chunk pointwise -> sxn h[0:128] + outputs ----
#pragma unroll
        for (int rg = 0; rg < 4; ++rg) {
            float gi = acc[0][rg] + bcq0;
            float gf = acc[1][rg] + bcq1;
            float gg = acc[2][rg] + bcq2;
            float go = acc[3][rg] + bcq3;
            float cn = sigf(gf) * cr[rg] + sigf(gi) * tanh_fast(gg);
            cr[rg] = cn;
            float h = sigf(go) * tanh_fast(cn);
            sxn[lq * 4 + rg][HP + uq] = bf16_rne(h);
            outc[rg * HD] = h;                       // uq<128<150 always valid
        }
        // ---- stage x_{t+1} into sxn ----
        if (pf) {
            *(unsigned int*)&sxn[pr0][2 * pk0] = pk2bf(px0.x, px0.y);
            *(unsigned int*)&sxn[pr1][2 * pk1] = pk2bf(px1.x, px1.y);
            if (tid < 176)
                *(unsigned int*)&sxn[pr2][2 * pk2] = pk2bf(px2.x, px2.y);
        }
        bar_lds();   // B1: sxn (x_{t+1}, h[0:128]) + sge complete

        // swap buffers, advance output pointer
        { unsigned short (*tmp)[SXP] = sxc; sxc = sxn; sxn = tmp; }
        outc += (size_t)BATCH * HD;
    }

    // ---- epilogue: extra pointwise for t = TSTEPS-1 ----
    {
        float gi = sge[re][0][ce_c] + bce0;
        float gf = sge[re][1][ce_c] + bce1;
        float gg = sge[re][2][ce_c] + bce2;
        float go = sge[re][3][ce_c] + bce3;
        float cn = sigf(gf) * cex + sigf(gi) * tanh_fast(gg);
        float h = sigf(go) * tanh_fast(cn);
        if (ue < 150)
            outputs[((size_t)(TSTEPS - 1) * BATCH + row0 + re) * HD + ue] = h;
    }
}

// ---------------- stop-gate MLP v4 ----------------
// 512 blocks, grid-stride jobs (3-4 each, balanced 2 blocks/CU).
// Wave wv pinned to output-col tile ct=wv: its w1 tile lives in registers
// (wfr[10], loaded ONCE per block) -> zero w1 global traffic in the job loop.
// A-frags from sA for all 4 row-tiles. 3 barriers/job (end barrier removed:
// layer3 reads st2 only; next stage writes sA only -- disjoint).
#define SG_GRID 512
__global__ __launch_bounds__(256, 2)
void stop_gate(const float* __restrict__ x,
               const unsigned short* __restrict__ Wc,
               const float* __restrict__ b1,
               const float* __restrict__ w2, const float* __restrict__ b2,
               const float* __restrict__ w3, const float* __restrict__ b3,
               const float* __restrict__ outputs, float* __restrict__ outh,
               float* __restrict__ ys) {
    __shared__ unsigned short sA[64][SXP];   // [x|h] bf16, 42 KB
    __shared__ float st1[64][S1P];           // 17.4 KB (cols 50..63 computed zeros)
    __shared__ float st2[64][S2P];           // 7.2 KB (cols 25..27 zero)
    __shared__ float sw2p[26][W2P];          // row 25 = 0; cols 50,51 = 0
    __shared__ float sw3p[2][S2P];           // cols 25..27 = 0
    __shared__ float b1s[64], sb2[26], sb3[2];

    const int tid  = threadIdx.x;
    const int lane = tid & 63;
    const int wv   = tid >> 6;     // wave 0..3 == its ct tile
    const int lrow = lane & 15;
    const int lq   = lane >> 4;

    // ---- w1 tile (ct = wv) into registers, once per block ----
    shortx8 wfr[10];
    {
        const unsigned short* wp1 =
            Wc + (size_t)(640 + wv * 16 + lrow) * PITCHW + lq * 8;
#pragma unroll
        for (int kb = 0; kb < 10; ++kb)
            wfr[kb] = *(const shortx8*)(wp1 + kb * 32);
    }

    // ---- one-time init ----
    // zero only sA pad cols: 150..159 and 310..319 (uint pairs)
    for (int i = tid; i < 64 * 10; i += 256) {
        int r = i / 10, c = i - r * 10;
        int col = (c < 5) ? (150 + 2 * c) : (310 + 2 * (c - 5));
        *(unsigned int*)&sA[r][col] = 0;
    }
    // zero st2 pad cols 25..27 (col 25 also written as computed zero)
    for (int i = tid; i < 64 * 3; i += 256)
        st2[i / 3][25 + i % 3] = 0.0f;
    // weights (sw2p row 25 = zeros; sb2[25] = 0)
    for (int i = tid; i < 26 * W2P; i += 256) {
        int j = i / W2P, k = i - j * W2P;
        sw2p[j][k] = (j < 25 && k < 50) ? w2[j * 50 + k] : 0.0f;
    }
    if (tid < 2 * S2P) {
        int j = tid / S2P, k = tid - j * S2P;
        sw3p[j][k] = (k < 25) ? w3[j * 25 + k] : 0.0f;
    }
    if (tid < 64) b1s[tid] = (tid < 50) ? b1[tid] : 0.0f;
    if (tid < 26) sb2[tid] = (tid < 25) ? b2[tid] : 0.0f;
    if (tid < 2)  sb3[tid] = b3[tid];
    __syncthreads();

    const float bv = b1s[wv * 16 + lrow];   // this lane's layer1 bias (col wv*16+lrow)

    for (int jb = blockIdx.x; jb < GATED * 64; jb += SG_GRID) {
        const int t    = jb >> 6;                    // 0..29
        const int row0 = (jb & 63) * 64;             // batch row base

        // ---- stage [x_t | h_t] bf16; write outh for t == GATED-1 ----
        for (int i = tid; i < 64 * 75; i += 256) {
            int row = i / 75, kk = i - row * 75;
            size_t base = ((size_t)t * BATCH + row0 + row) * (size_t)XD;
            float2 xv = *(const float2*)(x + base + 2 * kk);
            float2 hv = *(const float2*)(outputs + base + 2 * kk);   // HD==XD
            *(unsigned int*)&sA[row][2 * kk]      = pk2bf(xv.x, xv.y);
            *(unsigned int*)&sA[row][HP + 2 * kk] = pk2bf(hv.x, hv.y);
            if (t == GATED - 1)
                *(float2*)&outh[(size_t)(row0 + row) * HD + 2 * kk] = hv;
        }
        __syncthreads();

        // ---- w1 MFMAs: wave wv = ct tile wv, rt = 0..3; fused bias+relu ----
#pragma unroll
        for (int rt = 0; rt < 4; ++rt) {
            floatx4 aw = {0.f, 0.f, 0.f, 0.f};
#pragma unroll
            for (int kb = 0; kb < 10; ++kb) {
                shortx8 a = *(const shortx8*)&sA[rt * 16 + lrow][kb * 32 + lq * 8];
                aw = __builtin_amdgcn_mfma_f32_16x16x32_bf16(a, wfr[kb], aw, 0, 0, 0);
            }
#pragma unroll
            for (int rg = 0; rg < 4; ++rg) {
                float v = aw[rg] + bv;
                st1[rt * 16 + lq * 4 + rg][wv * 16 + lrow] = v > 0.0f ? v : 0.0f;
            }
        }
        __syncthreads();

        // ---- layer2: j-pairs per thread, st1 row reused, + relu ----
        for (int u = tid; u < 64 * 13; u += 256) {
            int s = u / 13, jp = u - s * 13;
            int j0 = 2 * jp, j1 = j0 + 1;       // j1 == 25 -> zero row, harmless
            float a0 = sb2[j0], a1 = sb2[j1];
#pragma unroll
            for (int m = 0; m < 13; ++m) {
                floatx4 a4  = *(const floatx4*)&st1[s][4 * m];
                floatx4 w40 = *(const floatx4*)&sw2p[j0][4 * m];
                floatx4 w41 = *(const floatx4*)&sw2p[j1][4 * m];
                a0 = fmaf(w40[0], a4[0], a0);  a1 = fmaf(w41[0], a4[0], a1);
                a0 = fmaf(w40[1], a4[1], a0);  a1 = fmaf(w41[1], a4[1], a1);
                a0 = fmaf(w40[2], a4[2], a0);  a1 = fmaf(w41[2], a4[2], a1);
                a0 = fmaf(w40[3], a4[3], a0);  a1 = fmaf(w41[3], a4[3], a1);
            }
            st2[s][j0] = a0 > 0.0f ? a0 : 0.0f;
            st2[s][j1] = a1 > 0.0f ? a1 : 0.0f;   // j1==25 writes 0
        }
        __syncthreads();

        // ---- layer3 + relu + softmax(2) ----
        // (no trailing barrier: next stage writes sA only, disjoint from st2)
        if (tid < 64) {
            float z0 = sb3[0], z1 = sb3[1];
#pragma unroll
            for (int m = 0; m < 7; ++m) {
                floatx4 a4 = *(const floatx4*)&st2[tid][4 * m];
                floatx4 w0 = *(const floatx4*)&sw3p[0][4 * m];
                floatx4 w1v = *(const floatx4*)&sw3p[1][4 * m];
                z0 = fmaf(w0[0], a4[0], z0);  z1 = fmaf(w1v[0], a4[0], z1);
                z0 = fmaf(w0[1], a4[1], z0);  z1 = fmaf(w1v[1], a4[1], z1);
                z0 = fmaf(w0[2], a4[2], z0);  z1 = fmaf(w1v[2], a4[2], z1);
                z0 = fmaf(w0[3], a4[3], z0);  z1 = fmaf(w1v[3], a4[3], z1);
            }
            z0 = z0 > 0.0f ? z0 : 0.0f;
            z1 = z1 > 0.0f ? z1 : 0.0f;
            float mx = fmaxf(z0, z1);
            float e0 = __expf(z0 - mx), e1 = __expf(z1 - mx);
            float inv = rcp_f(e0 + e1);
            float2 y = {e0 * inv, e1 * inv};
            *(float2*)&ys[((size_t)t * BATCH + row0 + tid) * 2] = y;
        }
    }
}

extern "C" void kernel_launch(void* const* d_in, const int* in_sizes, int n_in,
                              void* d_out, int out_size, void* d_ws, size_t ws_size,
                              hipStream_t stream) {
    const float* x    = (const float*)d_in[0];
    const float* w_ih = (const float*)d_in[1];
    const float* w_hh = (const float*)d_in[2];
    const float* b_ih = (const float*)d_in[3];
    const float* b_hh = (const float*)d_in[4];
    const float* w1   = (const float*)d_in[5];
    const float* b1   = (const float*)d_in[6];
    const float* w2   = (const float*)d_in[7];
    const float* b2   = (const float*)d_in[8];
    const float* w3   = (const float*)d_in[9];
    const float* b3   = (const float*)d_in[10];

    float* out = (float*)d_out;
    unsigned short* Wc  = (unsigned short*)d_ws;           // 704*328 bf16
    float*          bcp = (float*)(Wc + WROWS * PITCHW);   // 640

    pack_weights<<<256, 256, 0, stream>>>(w_ih, w_hh, b_ih, b_hh, w1, Wc, bcp);

    lstm_main<<<NBLK, NT, 0, stream>>>(
        x, Wc, bcp, out + OFF_OUTPUTS);

    stop_gate<<<SG_GRID, 256, 0, stream>>>(
        x, Wc, b1, w2, b2, w3, b3, out + OFF_OUTPUTS, out, out + OFF_YS);
}